// Round 1
// baseline (349.127 us; speedup 1.0000x reference)
//
#include <hip/hip_runtime.h>

#define RM_EPS 1e-10f
#define RM_N   128          // samples per ray
#define RM_F   3            // feature channels

// One 64-lane wave per ray; lane l handles samples 2l and 2l+1.
__global__ __launch_bounds__(256) void raymarch_kernel(
    const float* __restrict__ dens,   // (n_rays, 128)
    const float* __restrict__ feat,   // (n_rays, 128, 3)
    const float* __restrict__ len,    // (n_rays, 128)
    float* __restrict__ out,          // (n_rays, 4)
    int n_rays)
{
    const int wave = (int)((blockIdx.x * blockDim.x + threadIdx.x) >> 6);
    const int lane = (int)(threadIdx.x & 63);
    if (wave >= n_rays) return;
    const long long ray = wave;

    // Coalesced vector loads
    const float2 d2 = ((const float2*)(dens + ray * RM_N))[lane];
    const float2 l2 = ((const float2*)(len  + ray * RM_N))[lane];
    const float2* fp = (const float2*)(feat + ray * (RM_N * RM_F)) + lane * 3;
    const float2 fa = fp[0];  // f0[0], f0[1]
    const float2 fb = fp[1];  // f0[2], f1[0]
    const float2 fc = fp[2];  // f1[1], f1[2]

    // absorption terms
    const float t0 = 1.0f + RM_EPS - d2.x;
    const float t1 = 1.0f + RM_EPS - d2.y;

    // Inclusive multiplicative scan of per-lane product across the wave
    float p = t0 * t1;
    #pragma unroll
    for (int off = 1; off < 64; off <<= 1) {
        float q = __shfl_up(p, off);
        p *= (lane >= off) ? q : 1.0f;
    }
    // Exclusive prefix product (absorption before sample 2l)
    float e = __shfl_up(p, 1);
    if (lane == 0) e = 1.0f;

    const float w0 = d2.x * e;        // weight for sample 2l
    const float w1 = d2.y * e * t0;   // weight for sample 2l+1

    float s0 = w0 * fa.x + w1 * fb.y; // feature channel 0
    float s1 = w0 * fa.y + w1 * fc.x; // feature channel 1
    float s2 = w0 * fb.x + w1 * fc.y; // feature channel 2
    float sd = w0 * l2.x + w1 * l2.y; // depth
    float sa = w0 + w1;               // alpha

    // Wave reduction (butterfly)
    #pragma unroll
    for (int off = 32; off > 0; off >>= 1) {
        s0 += __shfl_xor(s0, off);
        s1 += __shfl_xor(s1, off);
        s2 += __shfl_xor(s2, off);
        sd += __shfl_xor(sd, off);
        sa += __shfl_xor(sa, off);
    }
    const float last_len = __shfl(l2.y, 63);  // lengths[..., -1]

    if (lane == 0) {
        const float bg = 1.0f - sa;
        float4 o;
        o.x = s0 + bg;
        o.y = s1 + bg;
        o.z = s2 + bg;
        o.w = sd + bg * last_len;
        ((float4*)out)[ray] = o;
    }
}

extern "C" void kernel_launch(void* const* d_in, const int* in_sizes, int n_in,
                              void* d_out, int out_size, void* d_ws, size_t ws_size,
                              hipStream_t stream) {
    const float* dens = (const float*)d_in[0];  // rays_densities (B,R,N,1)
    const float* feat = (const float*)d_in[1];  // rays_features  (B,R,N,3)
    const float* len  = (const float*)d_in[2];  // lengths        (B,R,N)
    float* out = (float*)d_out;                 // (B,R,4)

    const int n_rays = in_sizes[0] / RM_N;      // B*R = 131072
    const int waves_per_block = 256 / 64;
    const int grid = (n_rays + waves_per_block - 1) / waves_per_block;
    raymarch_kernel<<<grid, 256, 0, stream>>>(dens, feat, len, out, n_rays);
}